// Round 1
// baseline (309.029 us; speedup 1.0000x reference)
//
#include <hip/hip_runtime.h>
#include <hip/hip_bf16.h>

// C[M,N] = A[M,K] @ B[N,K]^T, fp32 inputs, fp32 output, bf16 MFMA compute.
// Phase 1: convert A,B fp32 -> bf16 into d_ws (RNE).
// Phase 2: m97-style 128x128-tile bf16 GEMM (global_load_lds w=16, 16x16x32 MFMA).

typedef __bf16 bf16x8 __attribute__((ext_vector_type(8)));
typedef float f32x4 __attribute__((ext_vector_type(4)));

#define TM 128
#define TN 128
#define BK 32

__device__ __forceinline__ void load_lds16(const __bf16* g, __bf16* l) {
    __builtin_amdgcn_global_load_lds(
        (const __attribute__((address_space(1))) void*)g,
        (__attribute__((address_space(3))) void*)l,
        16 /*bytes*/, 0 /*offset*/, 0 /*aux*/);
}

__global__ void cvt_f32_to_bf16(const float* __restrict__ src,
                                __hip_bfloat16* __restrict__ dst, int n8) {
    int i = blockIdx.x * blockDim.x + threadIdx.x;
    if (i >= n8) return;
    const float4* p = (const float4*)src + (size_t)i * 2;
    float4 a = p[0];
    float4 b = p[1];
    union { __hip_bfloat16 h[8]; uint4 u; } o;
    o.h[0] = __float2bfloat16(a.x); o.h[1] = __float2bfloat16(a.y);
    o.h[2] = __float2bfloat16(a.z); o.h[3] = __float2bfloat16(a.w);
    o.h[4] = __float2bfloat16(b.x); o.h[5] = __float2bfloat16(b.y);
    o.h[6] = __float2bfloat16(b.z); o.h[7] = __float2bfloat16(b.w);
    ((uint4*)dst)[i] = o.u;
}

// 128x128 tile, BK=32, 256 threads (4 waves in 2x2), each wave 64x64 = 4x4 MFMAs.
__global__ __launch_bounds__(256, 2) void gemm_bt_bf16(
    const __bf16* __restrict__ A,  // [M,K] row-major bf16
    const __bf16* __restrict__ B,  // [N,K] row-major bf16
    float* __restrict__ C,         // [M,N] row-major fp32
    int M, int N, int K) {
    __shared__ __bf16 As[TM * BK];  // 8 KiB, row-major [128][32]
    __shared__ __bf16 Bs[TN * BK];  // 8 KiB

    const int tid = threadIdx.x;
    const int wave = tid >> 6;
    const int lane = tid & 63;
    const int bn = blockIdx.x;
    const int bm = blockIdx.y;

    // ---- staging addressing: wave w covers 16 rows/round, lane -> (row, k-quarter)
    const int srow = lane >> 2;            // 0..15
    const int scol = (lane & 3) << 3;      // 0,8,16,24 (bf16 elems)
    const __bf16* ga = A + ((size_t)bm * TM + wave * 16 + srow) * (size_t)K + scol;
    const __bf16* gb = B + ((size_t)bn * TN + wave * 16 + srow) * (size_t)K + scol;
    const size_t g64 = (size_t)64 * K;     // 64-row advance for round 1
    __bf16* la = As + wave * 512;          // wave writes 512 elems (1024 B)/round
    __bf16* lb = Bs + wave * 512;

    // ---- fragment addressing
    const int wm = (wave >> 1) << 6;       // wave row base in tile
    const int wn = (wave & 1) << 6;        // wave col base in tile
    const int fr = lane & 15;
    const int fk = (lane >> 4) << 3;       // quad*8
    const __bf16* pa = As + (wm + fr) * BK + fk;
    const __bf16* pb = Bs + (wn + fr) * BK + fk;

    f32x4 acc[4][4];
#pragma unroll
    for (int i = 0; i < 4; ++i)
#pragma unroll
        for (int j = 0; j < 4; ++j) acc[i][j] = (f32x4){0.f, 0.f, 0.f, 0.f};

    for (int k0 = 0; k0 < K; k0 += BK) {
        // stage A-tile (2 rounds of 64 rows) and B-tile
        load_lds16(ga + k0, la);
        load_lds16(ga + g64 + k0, la + 2048);
        load_lds16(gb + k0, lb);
        load_lds16(gb + g64 + k0, lb + 2048);
        __syncthreads();  // compiler emits s_waitcnt vmcnt(0) before s_barrier

        bf16x8 af[4], bf[4];
#pragma unroll
        for (int i = 0; i < 4; ++i) af[i] = *(const bf16x8*)(pa + i * (16 * BK));
#pragma unroll
        for (int j = 0; j < 4; ++j) bf[j] = *(const bf16x8*)(pb + j * (16 * BK));
#pragma unroll
        for (int i = 0; i < 4; ++i)
#pragma unroll
            for (int j = 0; j < 4; ++j)
                acc[i][j] = __builtin_amdgcn_mfma_f32_16x16x32_bf16(
                    af[i], bf[j], acc[i][j], 0, 0, 0);
        __syncthreads();
    }

    // ---- epilogue: C/D layout col=lane&15, row=(lane>>4)*4+reg  [m89/m91]
    const int cq = (lane >> 4) << 2;
    const int cc = lane & 15;
    float* Cbase = C + ((size_t)bm * TM + wm + cq) * (size_t)N + (size_t)bn * TN + wn + cc;
#pragma unroll
    for (int i = 0; i < 4; ++i)
#pragma unroll
        for (int r = 0; r < 4; ++r) {
            float* row = Cbase + (size_t)(16 * i + r) * N;
#pragma unroll
            for (int j = 0; j < 4; ++j) row[16 * j] = acc[i][j][r];
        }
}

// Fallback (only if ws too small): same GEMM but converts fp32->bf16 during
// LDS staging (no workspace, no global_load_lds).
__global__ __launch_bounds__(256, 2) void gemm_bt_f32in(
    const float* __restrict__ A, const float* __restrict__ B,
    float* __restrict__ C, int M, int N, int K) {
    __shared__ __bf16 As[TM * BK];
    __shared__ __bf16 Bs[TN * BK];

    const int tid = threadIdx.x;
    const int wave = tid >> 6;
    const int lane = tid & 63;
    const int bn = blockIdx.x;
    const int bm = blockIdx.y;

    const int frow = tid >> 3;             // 0..31
    const int fcol = (tid & 7) << 2;       // fp32 elems, 0..28
    const float* gaf = A + ((size_t)bm * TM + frow) * (size_t)K + fcol;
    const float* gbf = B + ((size_t)bn * TN + frow) * (size_t)K + fcol;

    const int wm = (wave >> 1) << 6;
    const int wn = (wave & 1) << 6;
    const int fr = lane & 15;
    const int fk = (lane >> 4) << 3;
    const __bf16* pa = As + (wm + fr) * BK + fk;
    const __bf16* pb = Bs + (wn + fr) * BK + fk;

    f32x4 acc[4][4];
#pragma unroll
    for (int i = 0; i < 4; ++i)
#pragma unroll
        for (int j = 0; j < 4; ++j) acc[i][j] = (f32x4){0.f, 0.f, 0.f, 0.f};

    for (int k0 = 0; k0 < K; k0 += BK) {
#pragma unroll
        for (int rd = 0; rd < 4; ++rd) {
            float4 va = *(const float4*)(gaf + (size_t)(rd * 32) * K + k0);
            float4 vb = *(const float4*)(gbf + (size_t)(rd * 32) * K + k0);
            union { __hip_bfloat16 h[4]; uint2 u; } oa, ob;
            oa.h[0] = __float2bfloat16(va.x); oa.h[1] = __float2bfloat16(va.y);
            oa.h[2] = __float2bfloat16(va.z); oa.h[3] = __float2bfloat16(va.w);
            ob.h[0] = __float2bfloat16(vb.x); ob.h[1] = __float2bfloat16(vb.y);
            ob.h[2] = __float2bfloat16(vb.z); ob.h[3] = __float2bfloat16(vb.w);
            *(uint2*)(As + (frow + rd * 32) * BK + fcol) = oa.u;
            *(uint2*)(Bs + (frow + rd * 32) * BK + fcol) = ob.u;
        }
        __syncthreads();

        bf16x8 af[4], bf[4];
#pragma unroll
        for (int i = 0; i < 4; ++i) af[i] = *(const bf16x8*)(pa + i * (16 * BK));
#pragma unroll
        for (int j = 0; j < 4; ++j) bf[j] = *(const bf16x8*)(pb + j * (16 * BK));
#pragma unroll
        for (int i = 0; i < 4; ++i)
#pragma unroll
            for (int j = 0; j < 4; ++j)
                acc[i][j] = __builtin_amdgcn_mfma_f32_16x16x32_bf16(
                    af[i], bf[j], acc[i][j], 0, 0, 0);
        __syncthreads();
    }

    const int cq = (lane >> 4) << 2;
    const int cc = lane & 15;
    float* Cbase = C + ((size_t)bm * TM + wm + cq) * (size_t)N + (size_t)bn * TN + wn + cc;
#pragma unroll
    for (int i = 0; i < 4; ++i)
#pragma unroll
        for (int r = 0; r < 4; ++r) {
            float* row = Cbase + (size_t)(16 * i + r) * N;
#pragma unroll
            for (int j = 0; j < 4; ++j) row[16 * j] = acc[i][j][r];
        }
}

extern "C" void kernel_launch(void* const* d_in, const int* in_sizes, int n_in,
                              void* d_out, int out_size, void* d_ws, size_t ws_size,
                              hipStream_t stream) {
    const float* A = (const float*)d_in[0];  // [8, 1024, 4096] contiguous = [M,K]
    const float* B = (const float*)d_in[1];  // [N,K]
    float* C = (float*)d_out;

    const int K = 4096;
    const int aN = in_sizes[0];      // M*K = 33554432
    const int bN = in_sizes[1];      // N*K = 4194304
    const int M = aN / K;            // 8192
    const int N = bN / K;            // 1024

    dim3 grid(N / TN, M / TM);       // (8, 64)
    const size_t need = ((size_t)aN + (size_t)bN) * sizeof(__hip_bfloat16);

    if (ws_size >= need) {
        __hip_bfloat16* Abf = (__hip_bfloat16*)d_ws;
        __hip_bfloat16* Bbf = Abf + (size_t)aN;
        cvt_f32_to_bf16<<<aN / 8 / 256, 256, 0, stream>>>(A, Abf, aN / 8);
        cvt_f32_to_bf16<<<bN / 8 / 256, 256, 0, stream>>>(B, Bbf, bN / 8);
        gemm_bt_bf16<<<grid, 256, 0, stream>>>(
            (const __bf16*)Abf, (const __bf16*)Bbf, C, M, N, K);
    } else {
        gemm_bt_f32in<<<grid, 256, 0, stream>>>(A, B, C, M, N, K);
    }
}